// Round 2
// baseline (707.190 us; speedup 1.0000x reference)
//
#include <hip/hip_runtime.h>
#include <hip/hip_bf16.h>
#include <stdint.h>

#define BATCH 256
#define NP    196
#define PP    768
#define DD    768
#define FM    40
#define FU    156
#define ROWS  39936   // 256*156

// output element offsets (f32 elements, concatenated in return order)
#define O_UE 0ull          // unmasked_embeddings [256,156,768]
#define O_ME 30670848ull   // masked_embeddings   [256,40,768]
#define O_UP 38535168ull   // unmasked_positions  [256,156,768]
#define O_MI 69206016ull   // mask_indices        [256,40]   (as float)
#define O_UI 69216256ull   // unmask_indices      [256,156]  (as float)

typedef __attribute__((ext_vector_type(8))) short short8;
typedef __attribute__((ext_vector_type(4))) float f32x4;

__device__ __forceinline__ unsigned short bf16_rne(float x) {
    unsigned u = __float_as_uint(x);
    u += 0x7FFFu + ((u >> 16) & 1u);
    return (unsigned short)(u >> 16);
}
__device__ __forceinline__ float bf16_f(unsigned short h) {
    return __uint_as_float(((unsigned)h) << 16);
}

__device__ __forceinline__ void gl_lds16(const void* gsrc, void* ldst) {
    __builtin_amdgcn_global_load_lds(
        (const __attribute__((address_space(1))) unsigned*)gsrc,
        (__attribute__((address_space(3))) unsigned*)ldst, 16, 0, 0);
}

// ---------------------------------------------------------------------------
// Kernel 1: W -> wt tiles [kt(24)][ct(6)][plane(2)][row(128)][slot(4)x16B],
// exact LDS image incl. XOR slot swizzle (slot = g ^ ((row>>1)&3)).
// Chunk content: 8 bf16, k32 = e<4 ? 4g+e : 12+4g+e  (perm for ds_read_b128).
// ---------------------------------------------------------------------------
__global__ __launch_bounds__(256) void prep_w_kernel(
    const float* __restrict__ W,
    unsigned short* __restrict__ wt) {
    const int j  = blockIdx.x * 256 + threadIdx.x;  // 0..511 (hi-plane chunk id)
    const int ct = blockIdx.y;                      // 0..5
    const int kt = blockIdx.z;                      // 0..23
    const int row  = j >> 2;
    const int slot = j & 3;
    const int g    = slot ^ ((row >> 1) & 3);
    const int d    = ct * 128 + row;
    alignas(16) unsigned short hi[8];
    alignas(16) unsigned short lo[8];
#pragma unroll
    for (int e = 0; e < 8; ++e) {
        int k32 = (e < 4) ? (4 * g + e) : (12 + 4 * g + e);
        float x = W[(size_t)(kt * 32 + k32) * DD + d];
        unsigned short h = bf16_rne(x);
        hi[e] = h;
        lo[e] = bf16_rne(x - bf16_f(h));
    }
    unsigned short* dst = wt + ((size_t)(kt * 6 + ct) * 1024 + j) * 8;
    *(uint4*)dst          = *(const uint4*)hi;
    *(uint4*)(dst + 4096) = *(const uint4*)lo;   // lo plane = chunk j+512
}

// ---------------------------------------------------------------------------
// Kernel 2a/2b: mtok = mask_token @ W + b  (deterministic 2-stage)
// ---------------------------------------------------------------------------
__global__ __launch_bounds__(256) void mtok_part_kernel(
    const float* __restrict__ mask_token,
    const float* __restrict__ W,
    float* __restrict__ part) {
    const int j = blockIdx.x;        // 0..11, p range [64j, 64j+64)
    const int tid = threadIdx.x;
#pragma unroll
    for (int s = 0; s < 3; ++s) {
        int d = tid + s * 256;
        float acc = 0.f;
        for (int p = j * 64; p < j * 64 + 64; ++p)
            acc += mask_token[p] * W[(size_t)p * DD + d];
        part[(size_t)j * DD + d] = acc;
    }
}
__global__ __launch_bounds__(256) void mtok_red_kernel(
    const float* __restrict__ part,
    const float* __restrict__ bias,
    float* __restrict__ mtok_out) {
    int d = blockIdx.x * 256 + threadIdx.x;
    float acc = bias[d];
#pragma unroll
    for (int j = 0; j < 12; ++j) acc += part[(size_t)j * DD + d];
    mtok_out[d] = acc;
}

// ---------------------------------------------------------------------------
// Kernel 3: per-image selection (bitonic sort reproduces jax.lax.top_k).
// ---------------------------------------------------------------------------
__global__ __launch_bounds__(256) void select_kernel(
    const float* __restrict__ patches,
    const float* __restrict__ rand_u,
    float* __restrict__ out,
    int* __restrict__ gidx,
    int* __restrict__ pidx,
    int* __restrict__ midx,
    int* __restrict__ valid_arr) {

    const int b = blockIdx.x;
    const int tid = threadIdx.x;
    __shared__ unsigned long long key[256];
    __shared__ int s_flag[256];
    __shared__ int s_scan[256];
    __shared__ int wsum[4];

    int v = 0;
    if (tid < NP) {
        const float* row = patches + ((size_t)b * NP + tid) * PP;
        for (int p = 0; p < PP; ++p) {
            if (row[p] != 0.0f) { v = 1; break; }
        }
    }
    unsigned long long bal = __ballot(v != 0);
    if ((tid & 63) == 0) wsum[tid >> 6] = __popcll(bal);
    __syncthreads();
    int count = wsum[0] + wsum[1] + wsum[2] + wsum[3];
    bool valid_image = (count >= 20) && (ceilf((float)count * 0.4f) >= 40.0f);

    unsigned long long k = 0ull;
    if (tid < NP) {
        float u = rand_u[(size_t)b * NP + tid];
        // match jax bit-exactly: no fma contraction
        float score = v ? __fadd_rn(1000.0f, __fmul_rn(1000.0f, u))
                        : __fmul_rn(10.0f, u);
        k = (((unsigned long long)__float_as_uint(score)) << 32) |
            (unsigned long long)(unsigned)(~tid);
    }
    key[tid] = k;
    __syncthreads();

    for (int kk = 2; kk <= 256; kk <<= 1) {
        for (int j = kk >> 1; j > 0; j >>= 1) {
            int ixj = tid ^ j;
            if (ixj > tid) {
                unsigned long long a = key[tid], c = key[ixj];
                bool desc = ((tid & kk) == 0);
                if (desc ? (a < c) : (a > c)) { key[tid] = c; key[ixj] = a; }
            }
            __syncthreads();
        }
    }

    int m_out = 0;
    if (tid < FM) {
        int idx = (int)(~(unsigned)(key[tid] & 0xFFFFFFFFull));
        m_out = valid_image ? idx : 0;
        midx[b * FM + tid] = m_out;
        out[O_MI + (size_t)b * FM + tid] = (float)m_out;
    }
    s_flag[tid] = 0;
    __syncthreads();
    if (tid < FM) s_flag[m_out] = 1;
    __syncthreads();

    int x = (tid < NP) ? (1 - s_flag[tid]) : 0;
    s_scan[tid] = x;
    __syncthreads();
    for (int off = 1; off < 256; off <<= 1) {
        int t2 = (tid >= off) ? s_scan[tid - off] : 0;
        __syncthreads();
        s_scan[tid] += t2;
        __syncthreads();
    }
    int pos = s_scan[tid] - x;

    if (valid_image) {
        if (tid < NP && !s_flag[tid] && pos < FU) {
            gidx[(size_t)b * FU + pos] = b * NP + tid;
            pidx[(size_t)b * FU + pos] = tid;
            out[O_UI + (size_t)b * FU + pos] = (float)tid;
        }
    } else {
        if (tid < FU) {
            gidx[(size_t)b * FU + tid] = b * NP + tid;
            pidx[(size_t)b * FU + tid] = tid;
            out[O_UI + (size_t)b * FU + tid] = (float)tid;
        }
    }
    if (tid == 0) valid_arr[b] = valid_image ? 1 : 0;
}

// ---------------------------------------------------------------------------
// Kernel 4: gather-fused patch conversion: row r -> bf16 hi|lo planes in
// fragment chunk order: [row][plane(2)][kt(24)][g(4)][8 elems]  (3072 B/row)
// ---------------------------------------------------------------------------
__global__ __launch_bounds__(192) void prep_p_kernel(
    const float* __restrict__ patches,
    const int* __restrict__ gidx,
    char* __restrict__ pat_bf) {
    const int r = blockIdx.x;
    const int t = threadIdx.x;             // 0..191, 4 f32 each
    const float* src = patches + (size_t)gidx[r] * PP;
    float4 v4 = *(const float4*)(src + 4 * t);
    const int kt = t >> 3;
    const int q  = t & 7;
    const int g  = q & 3;
    const int half = q >> 2;
    float vs[4] = {v4.x, v4.y, v4.z, v4.w};
    unsigned long long hp = 0, lp = 0;
#pragma unroll
    for (int e = 0; e < 4; ++e) {
        unsigned short h = bf16_rne(vs[e]);
        unsigned short l = bf16_rne(vs[e] - bf16_f(h));
        hp |= ((unsigned long long)h) << (16 * e);
        lp |= ((unsigned long long)l) << (16 * e);
    }
    char* dst = pat_bf + (size_t)r * 3072 + kt * 64 + g * 16 + half * 8;
    *(unsigned long long*)dst          = hp;
    *(unsigned long long*)(dst + 1536) = lp;
}

// ---------------------------------------------------------------------------
// Kernel 5: gathered GEMM, split-bf16 x3 MFMA. 128 rows x 128 d tile,
// 4 waves (2 d x 2 row), BK=32, W via global_load_lds double-buffer (1
// barrier/K-step), B per-lane 16B loads (PRE=1) or in-reg convert (PRE=0).
// ---------------------------------------------------------------------------
template <int PRE>
__device__ __forceinline__ void fetchB(int KT, short8 (&BH)[4], short8 (&BL)[4],
                                       const char* const (&pb)[4],
                                       const float* const (&prow)[4], int g) {
    if constexpr (PRE) {
#pragma unroll
        for (int ci = 0; ci < 4; ++ci) {
            const char* p = pb[ci] + KT * 64;
            BH[ci] = *(const short8*)p;
            BL[ci] = *(const short8*)(p + 1536);
        }
    } else {
#pragma unroll
        for (int ci = 0; ci < 4; ++ci) {
            const float* p = prow[ci] + KT * 32 + 4 * g;
            const float4 a  = *(const float4*)p;
            const float4 b2 = *(const float4*)(p + 16);
            float vs[8] = {a.x, a.y, a.z, a.w, b2.x, b2.y, b2.z, b2.w};
            short8 h8, l8;
#pragma unroll
            for (int e = 0; e < 8; ++e) {
                unsigned short h = bf16_rne(vs[e]);
                h8[e] = (short)h;
                l8[e] = (short)bf16_rne(vs[e] - bf16_f(h));
            }
            BH[ci] = h8;
            BL[ci] = l8;
        }
    }
}

template <int PRE>
__global__ __launch_bounds__(256) void gemm_kernel(
    const float* __restrict__ patches,
    const char* __restrict__ pat_bf,
    const unsigned short* __restrict__ wt,
    const float* __restrict__ bias,
    const float* __restrict__ pos_table,
    const int* __restrict__ gidx,
    const int* __restrict__ pidx,
    float* __restrict__ out) {

    __shared__ __align__(16) char ldsb[32768];   // 2 buf x [plane 2][row 128][4x16B]

    const int tid = threadIdx.x;
    const int l   = tid & 63;
    const int w   = tid >> 6;
    const int wd  = w >> 1;
    const int wp  = w & 1;
    const int l15 = l & 15;
    const int g   = l >> 4;
    const int slot = g ^ ((l15 >> 1) & 3);

    // XCD-chunked bijective swizzle (nwg=1872, 1872%8==0 -> 234/XCD)
    int lin = blockIdx.y * 6 + blockIdx.x;
    lin = (lin & 7) * 234 + (lin >> 3);
    const int ct = lin % 6;
    const int rt = lin / 6;

    int rflat[4];
    int ppos[4];
    const char* pb[4]   = {nullptr, nullptr, nullptr, nullptr};
    const float* prow[4] = {nullptr, nullptr, nullptr, nullptr};
#pragma unroll
    for (int ci = 0; ci < 4; ++ci) {
        int r = rt * 128 + wp * 64 + ci * 16 + l15;
        rflat[ci] = r;
        ppos[ci] = pidx[r];
        if constexpr (PRE) {
            pb[ci] = pat_bf + (size_t)r * 3072 + g * 16;
        } else {
            prow[ci] = patches + (size_t)gidx[r] * PP;
        }
    }

    f32x4 acc[4][4];
    const f32x4 z = {0.f, 0.f, 0.f, 0.f};
#pragma unroll
    for (int mi = 0; mi < 4; ++mi)
#pragma unroll
        for (int ci = 0; ci < 4; ++ci) acc[mi][ci] = z;

#define STAGE(BUF, KT)                                                         \
    {                                                                          \
        const char* s0 = (const char*)wt + (size_t)((KT)*6 + ct) * 16384;      \
        _Pragma("unroll")                                                      \
        for (int c = 0; c < 4; ++c) {                                          \
            gl_lds16(s0 + ((c * 4 + w) * 64 + l) * 16,                         \
                     ldsb + (BUF)*16384 + (c * 4 + w) * 1024);                 \
        }                                                                      \
    }

#define COMPUTE(BUF, BH, BL)                                                   \
    _Pragma("unroll")                                                          \
    for (int mi = 0; mi < 4; ++mi) {                                           \
        const char* wb = ldsb + (BUF)*16384 +                                  \
                         (wd * 64 + mi * 16 + l15) * 64 + slot * 16;           \
        short8 wh = *(const short8*)wb;                                        \
        short8 wl = *(const short8*)(wb + 8192);                               \
        _Pragma("unroll")                                                      \
        for (int ci = 0; ci < 4; ++ci) {                                       \
            acc[mi][ci] = __builtin_amdgcn_mfma_f32_16x16x32_bf16(             \
                wh, BH[ci], acc[mi][ci], 0, 0, 0);                             \
            acc[mi][ci] = __builtin_amdgcn_mfma_f32_16x16x32_bf16(             \
                wh, BL[ci], acc[mi][ci], 0, 0, 0);                             \
            acc[mi][ci] = __builtin_amdgcn_mfma_f32_16x16x32_bf16(             \
                wl, BH[ci], acc[mi][ci], 0, 0, 0);                             \
        }                                                                      \
    }

    short8 bhA[4], blA[4], bhB[4], blB[4];
    fetchB<PRE>(0, bhA, blA, pb, prow, g);
    STAGE(0, 0);

    for (int kt = 0; kt < 24; kt += 2) {
        __syncthreads();                       // buf0(kt) ready; all reads of buf1 done
        STAGE(1, kt + 1);
        fetchB<PRE>(kt + 1, bhB, blB, pb, prow, g);
        COMPUTE(0, bhA, blA);
        __syncthreads();                       // buf1(kt+1) ready; reads of buf0 done
        if (kt + 2 < 24) {
            STAGE(0, kt + 2);
            fetchB<PRE>(kt + 2, bhA, blA, pb, prow, g);
        }
        COMPUTE(1, bhB, blB);
    }
#undef STAGE
#undef COMPUTE

    // epilogue: out = acc + bias + pos ; also emit gathered positions
#pragma unroll
    for (int mi = 0; mi < 4; ++mi) {
        const int dc = ct * 128 + wd * 64 + mi * 16 + 4 * g;
        const float4 b4 = *(const float4*)(bias + dc);
#pragma unroll
        for (int ci = 0; ci < 4; ++ci) {
            const float4 p4 = *(const float4*)(pos_table + (size_t)ppos[ci] * DD + dc);
            f32x4 o = acc[mi][ci];
            float4 r;
            r.x = o[0] + b4.x + p4.x;
            r.y = o[1] + b4.y + p4.y;
            r.z = o[2] + b4.z + p4.z;
            r.w = o[3] + b4.w + p4.w;
            size_t ro = (size_t)rflat[ci] * DD + dc;
            *(float4*)(out + O_UE + ro) = r;
            *(float4*)(out + O_UP + ro) = p4;
        }
    }
}

// ---------------------------------------------------------------------------
// Kernel 6: masked_embeddings = validity * (mtok + pos[mask_idx])
// ---------------------------------------------------------------------------
__global__ __launch_bounds__(192) void masked_kernel(
    const float* __restrict__ pos_table,
    const float* __restrict__ mtok,
    const int* __restrict__ midx,
    const int* __restrict__ valid_arr,
    float* __restrict__ out) {
    const int j = blockIdx.x;
    const int b = blockIdx.y;
    const int d = threadIdx.x * 4;
    float4 r = {0.f, 0.f, 0.f, 0.f};
    if (valid_arr[b]) {
        int pi = midx[b * FM + j];
        const float4 m4 = *(const float4*)(mtok + d);
        const float4 p4 = *(const float4*)(pos_table + (size_t)pi * DD + d);
        r.x = m4.x + p4.x; r.y = m4.y + p4.y;
        r.z = m4.z + p4.z; r.w = m4.w + p4.w;
    }
    *(float4*)(out + O_ME + ((size_t)b * FM + j) * DD + d) = r;
}

// ---------------------------------------------------------------------------
extern "C" void kernel_launch(void* const* d_in, const int* in_sizes, int n_in,
                              void* d_out, int out_size, void* d_ws, size_t ws_size,
                              hipStream_t stream) {
    const float* patches   = (const float*)d_in[0];
    const float* rand_u    = (const float*)d_in[1];
    const float* W         = (const float*)d_in[2];
    const float* bias      = (const float*)d_in[3];
    const float* pos_table = (const float*)d_in[4];
    const float* mask_tok  = (const float*)d_in[5];
    float* out = (float*)d_out;

    char* ws = (char*)d_ws;
    int*            gidx   = (int*)(ws + 0);           // 159744 B
    int*            pidx   = (int*)(ws + 159744);      // 159744 B
    int*            midx   = (int*)(ws + 319488);      // 40960 B
    int*            valid  = (int*)(ws + 360448);      // 1024 B
    float*          mtok   = (float*)(ws + 361472);    // 3072 B
    float*          mpart  = (float*)(ws + 364544);    // 36864 B
    unsigned short* wt     = (unsigned short*)(ws + 401408);  // 2359296 B
    char*           pat_bf = ws + 2760704;             // 122683392 B

    const size_t NEEDED = 2760704ull + 122683392ull;
    const bool pre = (ws_size >= NEEDED);

    prep_w_kernel<<<dim3(2, 6, 24), dim3(256), 0, stream>>>(W, wt);
    mtok_part_kernel<<<dim3(12), dim3(256), 0, stream>>>(mask_tok, W, mpart);
    mtok_red_kernel<<<dim3(3), dim3(256), 0, stream>>>(mpart, bias, mtok);
    select_kernel<<<dim3(BATCH), dim3(256), 0, stream>>>(patches, rand_u, out,
                                                         gidx, pidx, midx, valid);
    if (pre) {
        prep_p_kernel<<<dim3(ROWS), dim3(192), 0, stream>>>(patches, gidx, pat_bf);
        gemm_kernel<1><<<dim3(6, 312), dim3(256), 0, stream>>>(
            patches, pat_bf, wt, bias, pos_table, gidx, pidx, out);
    } else {
        gemm_kernel<0><<<dim3(6, 312), dim3(256), 0, stream>>>(
            patches, pat_bf, wt, bias, pos_table, gidx, pidx, out);
    }
    masked_kernel<<<dim3(FM, BATCH), dim3(192), 0, stream>>>(pos_table, mtok,
                                                             midx, valid, out);
}

// Round 6
// 606.186 us; speedup vs baseline: 1.1666x; 1.1666x over previous
//
#include <hip/hip_runtime.h>
#include <hip/hip_bf16.h>
#include <stdint.h>

#define BATCH 256
#define NP    196
#define PP    768
#define DD    768
#define FM    40
#define FU    156
#define ROWS  39936   // 256*156
#define NGRP  312     // ROWS/128

// output element offsets (f32 elements, concatenated in return order)
#define O_UE 0ull          // unmasked_embeddings [256,156,768]
#define O_ME 30670848ull   // masked_embeddings   [256,40,768]
#define O_UP 38535168ull   // unmasked_positions  [256,156,768]
#define O_MI 69206016ull   // mask_indices        [256,40]   (as float)
#define O_UI 69216256ull   // unmask_indices      [256,156]  (as float)

typedef __attribute__((ext_vector_type(8))) short short8;
typedef __attribute__((ext_vector_type(4))) float f32x4;

__device__ __forceinline__ unsigned short bf16_rne(float x) {
    unsigned u = __float_as_uint(x);
    u += 0x7FFFu + ((u >> 16) & 1u);
    return (unsigned short)(u >> 16);
}
__device__ __forceinline__ float bf16_f(unsigned short h) {
    return __uint_as_float(((unsigned)h) << 16);
}

__device__ __forceinline__ void gl_lds16(const void* gsrc, void* ldst) {
    __builtin_amdgcn_global_load_lds(
        (const __attribute__((address_space(1))) unsigned*)gsrc,
        (__attribute__((address_space(3))) unsigned*)ldst, 16, 0, 0);
}

// ---------------------------------------------------------------------------
// Kernel 1: W -> wt tiles [kt(24)][ct(6)] of 16KB = [hi 8KB][lo 8KB],
// exact LDS image incl. XOR slot swizzle (slot = g ^ ((row>>1)&3)).
// Chunk content: 8 bf16, k32 = e<4 ? 4g+e : 12+4g+e.
// ---------------------------------------------------------------------------
__global__ __launch_bounds__(256) void prep_w_kernel(
    const float* __restrict__ W,
    unsigned short* __restrict__ wt) {
    const int j  = blockIdx.x * 256 + threadIdx.x;  // 0..511 (hi-plane chunk id)
    const int ct = blockIdx.y;                      // 0..5
    const int kt = blockIdx.z;                      // 0..23
    const int row  = j >> 2;
    const int slot = j & 3;
    const int g    = slot ^ ((row >> 1) & 3);
    const int d    = ct * 128 + row;
    alignas(16) unsigned short hi[8];
    alignas(16) unsigned short lo[8];
#pragma unroll
    for (int e = 0; e < 8; ++e) {
        int k32 = (e < 4) ? (4 * g + e) : (12 + 4 * g + e);
        float x = W[(size_t)(kt * 32 + k32) * DD + d];
        unsigned short h = bf16_rne(x);
        hi[e] = h;
        lo[e] = bf16_rne(x - bf16_f(h));
    }
    unsigned short* dst = wt + ((size_t)(kt * 6 + ct) * 1024 + j) * 8;
    *(uint4*)dst          = *(const uint4*)hi;
    *(uint4*)(dst + 4096) = *(const uint4*)lo;
}

// ---------------------------------------------------------------------------
// Kernel 2a/2b: mtok = mask_token @ W + b  (48-way parallel partials)
// ---------------------------------------------------------------------------
__global__ __launch_bounds__(256) void mtok_part_kernel(
    const float* __restrict__ mask_token,
    const float* __restrict__ W,
    float* __restrict__ part) {
    const int j = blockIdx.x;        // 0..47, p range [16j, 16j+16)
    const int tid = threadIdx.x;
#pragma unroll
    for (int s = 0; s < 3; ++s) {
        int d = tid + s * 256;
        float acc = 0.f;
#pragma unroll
        for (int pp = 0; pp < 16; ++pp) {
            int p = j * 16 + pp;
            acc += mask_token[p] * W[(size_t)p * DD + d];
        }
        part[(size_t)j * DD + d] = acc;
    }
}
__global__ __launch_bounds__(256) void mtok_red_kernel(
    const float* __restrict__ part,
    const float* __restrict__ bias,
    float* __restrict__ mtok_out) {
    int d = blockIdx.x * 256 + threadIdx.x;
    float acc = bias[d];
#pragma unroll
    for (int j = 0; j < 48; ++j) acc += part[(size_t)j * DD + d];
    mtok_out[d] = acc;
}

// ---------------------------------------------------------------------------
// Kernel 3: per-image selection (bitonic sort reproduces jax.lax.top_k).
// ---------------------------------------------------------------------------
__global__ __launch_bounds__(256) void select_kernel(
    const float* __restrict__ patches,
    const float* __restrict__ rand_u,
    float* __restrict__ out,
    int* __restrict__ gidx,
    int* __restrict__ pidx,
    int* __restrict__ midx,
    int* __restrict__ valid_arr) {

    const int b = blockIdx.x;
    const int tid = threadIdx.x;
    __shared__ unsigned long long key[256];
    __shared__ int s_flag[256];
    __shared__ int s_scan[256];
    __shared__ int wsum[4];

    int v = 0;
    if (tid < NP) {
        const float* row = patches + ((size_t)b * NP + tid) * PP;
        for (int p = 0; p < PP; ++p) {
            if (row[p] != 0.0f) { v = 1; break; }
        }
    }
    unsigned long long bal = __ballot(v != 0);
    if ((tid & 63) == 0) wsum[tid >> 6] = __popcll(bal);
    __syncthreads();
    int count = wsum[0] + wsum[1] + wsum[2] + wsum[3];
    bool valid_image = (count >= 20) && (ceilf((float)count * 0.4f) >= 40.0f);

    unsigned long long k = 0ull;
    if (tid < NP) {
        float u = rand_u[(size_t)b * NP + tid];
        float score = v ? __fadd_rn(1000.0f, __fmul_rn(1000.0f, u))
                        : __fmul_rn(10.0f, u);
        k = (((unsigned long long)__float_as_uint(score)) << 32) |
            (unsigned long long)(unsigned)(~tid);
    }
    key[tid] = k;
    __syncthreads();

    for (int kk = 2; kk <= 256; kk <<= 1) {
        for (int j = kk >> 1; j > 0; j >>= 1) {
            int ixj = tid ^ j;
            if (ixj > tid) {
                unsigned long long a = key[tid], c = key[ixj];
                bool desc = ((tid & kk) == 0);
                if (desc ? (a < c) : (a > c)) { key[tid] = c; key[ixj] = a; }
            }
            __syncthreads();
        }
    }

    int m_out = 0;
    if (tid < FM) {
        int idx = (int)(~(unsigned)(key[tid] & 0xFFFFFFFFull));
        m_out = valid_image ? idx : 0;
        midx[b * FM + tid] = m_out;
        out[O_MI + (size_t)b * FM + tid] = (float)m_out;
    }
    s_flag[tid] = 0;
    __syncthreads();
    if (tid < FM) s_flag[m_out] = 1;
    __syncthreads();

    int x = (tid < NP) ? (1 - s_flag[tid]) : 0;
    s_scan[tid] = x;
    __syncthreads();
    for (int off = 1; off < 256; off <<= 1) {
        int t2 = (tid >= off) ? s_scan[tid - off] : 0;
        __syncthreads();
        s_scan[tid] += t2;
        __syncthreads();
    }
    int pos = s_scan[tid] - x;

    if (valid_image) {
        if (tid < NP && !s_flag[tid] && pos < FU) {
            gidx[(size_t)b * FU + pos] = b * NP + tid;
            pidx[(size_t)b * FU + pos] = tid;
            out[O_UI + (size_t)b * FU + pos] = (float)tid;
        }
    } else {
        if (tid < FU) {
            gidx[(size_t)b * FU + tid] = b * NP + tid;
            pidx[(size_t)b * FU + tid] = tid;
            out[O_UI + (size_t)b * FU + tid] = (float)tid;
        }
    }
    if (tid == 0) valid_arr[b] = valid_image ? 1 : 0;
}

// ---------------------------------------------------------------------------
// Kernel 4: gather-fused patch conversion -> per-(kt, row-group) 16KB tiles:
// pat_bf[kt][grp] = [hi: 128 rows x 64B (XOR-swizzled slots)][lo: same 8KB].
// Block j handles rows 2j, 2j+1 (adjacent rows -> full-line stores).
// ---------------------------------------------------------------------------
__global__ __launch_bounds__(192) void prep_p_kernel(
    const float* __restrict__ patches,
    const int* __restrict__ gidx,
    char* __restrict__ pat_bf) {
    const int j = blockIdx.x;              // 0..ROWS/2-1
    const int t = threadIdx.x;             // 0..191
    const int kt = t >> 3;
    const int q  = t & 7;
    const int g  = q & 3;
    const int half = q >> 2;
#pragma unroll
    for (int rr = 0; rr < 2; ++rr) {
        const int r = 2 * j + rr;
        const float* src = patches + (size_t)gidx[r] * PP;
        float4 v4 = *(const float4*)(src + 4 * t);
        float vs[4] = {v4.x, v4.y, v4.z, v4.w};
        unsigned long long hp = 0, lp = 0;
#pragma unroll
        for (int e = 0; e < 4; ++e) {
            unsigned short h = bf16_rne(vs[e]);
            unsigned short l2 = bf16_rne(vs[e] - bf16_f(h));
            hp |= ((unsigned long long)h) << (16 * e);
            lp |= ((unsigned long long)l2) << (16 * e);
        }
        const int rl = r & 127;
        const int grp = r >> 7;
        const int slot = g ^ ((rl >> 1) & 3);
        char* dst = pat_bf + ((size_t)kt * NGRP + grp) * 16384 +
                    rl * 64 + slot * 16 + half * 8;
        *(unsigned long long*)dst          = hp;
        *(unsigned long long*)(dst + 8192) = lp;
    }
}

// ---------------------------------------------------------------------------
// Kernel 5: gathered GEMM, split-bf16 x3 MFMA, counted-vmcnt pipeline.
// Block 128 rows x 128 d, 4 waves, BK=32. W: 2 LDS buffers (depth-1,
// L2-resident). B: 3 LDS buffers (depth-2, HBM-latency cover). Raw
// s_barrier + s_waitcnt vmcnt(12) keeps 12 loads in flight across barriers.
// ---------------------------------------------------------------------------
__global__ __launch_bounds__(256) void gemm_kernel(
    const char* __restrict__ pat_bf,
    const unsigned short* __restrict__ wt,
    const float* __restrict__ bias,
    const float* __restrict__ pos_table,
    const int* __restrict__ pidx,
    float* __restrict__ out) {

    __shared__ __align__(16) char ldsW[2 * 16384];
    __shared__ __align__(16) char ldsB[3 * 16384];

    const int tid = threadIdx.x;
    const int l   = tid & 63;
    const int w   = tid >> 6;
    const int wd  = w >> 1;
    const int wp  = w & 1;
    const int l15 = l & 15;
    const int g   = l >> 4;
    const int soff = (g ^ ((l15 >> 1) & 3)) * 16;

    // XCD-chunked bijective swizzle (nwg=1872, 1872%8==0 -> 234/XCD);
    // ct fastest within an XCD chunk -> B tile reused 6x in-XCD-L2.
    int lin = blockIdx.x;
    lin = (lin & 7) * 234 + (lin >> 3);
    const int ct = lin % 6;
    const int rt = lin / 6;

    int rflat[4];
    int ppos[4];
#pragma unroll
    for (int ci = 0; ci < 4; ++ci) {
        int r = rt * 128 + wp * 64 + ci * 16 + l15;
        rflat[ci] = r;
        ppos[ci] = pidx[r];
    }

    f32x4 acc[4][4];
    const f32x4 z = {0.f, 0.f, 0.f, 0.f};
#pragma unroll
    for (int mi = 0; mi < 4; ++mi)
#pragma unroll
        for (int ci = 0; ci < 4; ++ci) acc[mi][ci] = z;

#define STAGE_W(BUF, KT)                                                       \
    {                                                                          \
        const char* s0 = (const char*)wt + (size_t)((KT)*6 + ct) * 16384;      \
        _Pragma("unroll")                                                      \
        for (int c = 0; c < 4; ++c)                                            \
            gl_lds16(s0 + ((c * 4 + w) * 64 + l) * 16,                         \
                     ldsW + (BUF)*16384 + (c * 4 + w) * 1024);                 \
    }
#define STAGE_B(BUF, KT)                                                       \
    {                                                                          \
        const char* s0 = pat_bf + ((size_t)(KT)*NGRP + rt) * 16384;            \
        _Pragma("unroll")                                                      \
        for (int c = 0; c < 4; ++c)                                            \
            gl_lds16(s0 + ((c * 4 + w) * 64 + l) * 16,                         \
                     ldsB + (BUF)*16384 + (c * 4 + w) * 1024);                 \
    }
#define COMPUTE(WBUF, BBUF)                                                    \
    {                                                                          \
        const char* wbase = ldsW + (WBUF)*16384;                               \
        const char* bbase = ldsB + (BBUF)*16384;                               \
        short8 BH[4], BL[4];                                                   \
        _Pragma("unroll")                                                      \
        for (int ci = 0; ci < 4; ++ci) {                                       \
            const char* bb = bbase + (wp * 64 + ci * 16 + l15) * 64 + soff;    \
            BH[ci] = *(const short8*)bb;                                       \
            BL[ci] = *(const short8*)(bb + 8192);                              \
        }                                                                      \
        _Pragma("unroll")                                                      \
        for (int mi = 0; mi < 4; ++mi) {                                       \
            const char* wb = wbase + (wd * 64 + mi * 16 + l15) * 64 + soff;    \
            short8 wh = *(const short8*)wb;                                    \
            short8 wl2 = *(const short8*)(wb + 8192);                          \
            _Pragma("unroll")                                                  \
            for (int ci = 0; ci < 4; ++ci) {                                   \
                acc[mi][ci] = __builtin_amdgcn_mfma_f32_16x16x32_bf16(         \
                    wh, BH[ci], acc[mi][ci], 0, 0, 0);                         \
                acc[mi][ci] = __builtin_amdgcn_mfma_f32_16x16x32_bf16(         \
                    wh, BL[ci], acc[mi][ci], 0, 0, 0);                         \
                acc[mi][ci] = __builtin_amdgcn_mfma_f32_16x16x32_bf16(         \
                    wl2, BH[ci], acc[mi][ci], 0, 0, 0);                        \
            }                                                                  \
        }                                                                      \
    }

    // prologue: W(0) + B(0) + B(1) in flight (12 loads)
    STAGE_W(0, 0);
    STAGE_B(0, 0);
    STAGE_B(1, 1);

    int wcur = 0;
    for (int k = 0; k < 24; ++k) {
        if (k < 23) STAGE_W(wcur ^ 1, k + 1);
        if (k < 22) STAGE_B((k + 2) % 3, k + 2);
        // steady state: keep W(k+1), B(k+1), B(k+2) = 12 loads in flight;
        // everything older (incl. W(k), B(k)) retired.
        if (k < 22) {
            asm volatile("s_waitcnt vmcnt(12)" ::: "memory");
        } else if (k == 22) {
            asm volatile("s_waitcnt vmcnt(8)" ::: "memory");
        } else {
            asm volatile("s_waitcnt vmcnt(0)" ::: "memory");
        }
        __builtin_amdgcn_sched_barrier(0);
        __builtin_amdgcn_s_barrier();   // buf[k] visible to all waves
        __builtin_amdgcn_sched_barrier(0);
        COMPUTE(wcur, k % 3);
        __builtin_amdgcn_sched_barrier(0);
        __builtin_amdgcn_s_barrier();   // all reads done -> next iter may overwrite
        wcur ^= 1;
    }
#undef STAGE_W
#undef STAGE_B
#undef COMPUTE

    // epilogue: out = acc + bias + pos ; also emit gathered positions
#pragma unroll
    for (int mi = 0; mi < 4; ++mi) {
        const int dc = ct * 128 + wd * 64 + mi * 16 + 4 * g;
        const float4 b4 = *(const float4*)(bias + dc);
#pragma unroll
        for (int ci = 0; ci < 4; ++ci) {
            const float4 p4 = *(const float4*)(pos_table + (size_t)ppos[ci] * DD + dc);
            f32x4 o = acc[mi][ci];
            float4 r;
            r.x = o[0] + b4.x + p4.x;
            r.y = o[1] + b4.y + p4.y;
            r.z = o[2] + b4.z + p4.z;
            r.w = o[3] + b4.w + p4.w;
            size_t ro = (size_t)rflat[ci] * DD + dc;
            *(float4*)(out + O_UE + ro) = r;
            *(float4*)(out + O_UP + ro) = p4;
        }
    }
}

// ---------------------------------------------------------------------------
// Kernel 6: masked_embeddings = validity * (mtok + pos[mask_idx])
// ---------------------------------------------------------------------------
__global__ __launch_bounds__(192) void masked_kernel(
    const float* __restrict__ pos_table,
    const float* __restrict__ mtok,
    const int* __restrict__ midx,
    const int* __restrict__ valid_arr,
    float* __restrict__ out) {
    const int j = blockIdx.x;
    const int b = blockIdx.y;
    const int d = threadIdx.x * 4;
    float4 r = {0.f, 0.f, 0.f, 0.f};
    if (valid_arr[b]) {
        int pi = midx[b * FM + j];
        const float4 m4 = *(const float4*)(mtok + d);
        const float4 p4 = *(const float4*)(pos_table + (size_t)pi * DD + d);
        r.x = m4.x + p4.x; r.y = m4.y + p4.y;
        r.z = m4.z + p4.z; r.w = m4.w + p4.w;
    }
    *(float4*)(out + O_ME + ((size_t)b * FM + j) * DD + d) = r;
}

// ---------------------------------------------------------------------------
extern "C" void kernel_launch(void* const* d_in, const int* in_sizes, int n_in,
                              void* d_out, int out_size, void* d_ws, size_t ws_size,
                              hipStream_t stream) {
    const float* patches   = (const float*)d_in[0];
    const float* rand_u    = (const float*)d_in[1];
    const float* W         = (const float*)d_in[2];
    const float* bias      = (const float*)d_in[3];
    const float* pos_table = (const float*)d_in[4];
    const float* mask_tok  = (const float*)d_in[5];
    float* out = (float*)d_out;

    char* ws = (char*)d_ws;
    int*            gidx   = (int*)(ws + 0);           // 159744 B
    int*            pidx   = (int*)(ws + 159744);      // 159744 B
    int*            midx   = (int*)(ws + 319488);      // 40960 B
    int*            valid  = (int*)(ws + 360448);      // 1024 B
    float*          mtok   = (float*)(ws + 361472);    // 3072 B
    float*          mpart  = (float*)(ws + 364544);    // 147456 B (48x768)
    unsigned short* wt     = (unsigned short*)(ws + 512000);  // 2359296 B
    char*           pat_bf = ws + 2871296;             // 122683392 B (24x312x16KB)

    prep_w_kernel<<<dim3(2, 6, 24), dim3(256), 0, stream>>>(W, wt);
    mtok_part_kernel<<<dim3(48), dim3(256), 0, stream>>>(mask_tok, W, mpart);
    mtok_red_kernel<<<dim3(3), dim3(256), 0, stream>>>(mpart, bias, mtok);
    select_kernel<<<dim3(BATCH), dim3(256), 0, stream>>>(patches, rand_u, out,
                                                         gidx, pidx, midx, valid);
    prep_p_kernel<<<dim3(ROWS / 2), dim3(192), 0, stream>>>(patches, gidx, pat_bf);
    gemm_kernel<<<dim3(1872), dim3(256), 0, stream>>>(pat_bf, wt, bias,
                                                      pos_table, pidx, out);
    masked_kernel<<<dim3(FM, BATCH), dim3(192), 0, stream>>>(pos_table, mtok,
                                                             midx, valid, out);
}